// Round 5
// baseline (304.540 us; speedup 1.0000x reference)
//
#include <hip/hip_runtime.h>

#define H 128
#define HC 64
#define NOUT 10

static constexpr int kN = 100000;
static constexpr int kE = 600000;
static constexpr int kG = 1000;

typedef __attribute__((ext_vector_type(8))) short short8v;
typedef __attribute__((ext_vector_type(4))) float f32x4;

__device__ __forceinline__ float4 ld4(const float* p) { return *(const float4*)p; }

// fp32 -> bf16 round-to-nearest-even
__device__ __forceinline__ unsigned f2bf(float f) {
    unsigned u = __float_as_uint(f);
    return (u + 0x7fffu + ((u >> 16) & 1u)) >> 16;
}
__device__ __forceinline__ unsigned f2bf2(float a, float b) {
    return f2bf(a) | (f2bf(b) << 16);
}
__device__ __forceinline__ float bf2f(unsigned short u) {
    return __uint_as_float(((unsigned)u) << 16);
}

// ---------------- histogram: cnt[keys[i]]++ ----------------
__global__ void k_hist(const int* __restrict__ keys, int* __restrict__ cnt, int n) {
    int i = blockIdx.x * blockDim.x + threadIdx.x;
    if (i < n) atomicAdd(&cnt[keys[i]], 1);
}

// ---------------- hierarchical scan ----------------
__global__ void k_scan_p1(const int* __restrict__ in, int* __restrict__ partial, int n) {
    __shared__ int red[256];
    int b = blockIdx.x, t = threadIdx.x;
    int base = b * 1024 + t * 4;
    int s = 0;
#pragma unroll
    for (int k = 0; k < 4; ++k) {
        int j = base + k;
        if (j < n) s += in[j];
    }
    red[t] = s;
    __syncthreads();
    for (int off = 128; off; off >>= 1) {
        if (t < off) red[t] += red[t + off];
        __syncthreads();
    }
    if (t == 0) partial[b] = red[0];
}

__global__ void k_scan_p2(int* __restrict__ partial, int* __restrict__ total_out, int nb) {
    __shared__ int ssum[1024];
    int t = threadIdx.x;
    int v = (t < nb) ? partial[t] : 0;
    ssum[t] = v;
    __syncthreads();
    for (int off = 1; off < 1024; off <<= 1) {
        int u = (t >= off) ? ssum[t - off] : 0;
        __syncthreads();
        ssum[t] += u;
        __syncthreads();
    }
    if (t < nb) partial[t] = ssum[t] - v;
    if (t == 1023 && total_out) *total_out = ssum[1023];
}

__global__ void k_scan_p3(const int* __restrict__ in, const int* __restrict__ partial,
                          int* __restrict__ out, int* __restrict__ cursor, int n) {
    __shared__ int red[256];
    int b = blockIdx.x, t = threadIdx.x;
    int base = b * 1024 + t * 4;
    int v[4];
    int s = 0;
#pragma unroll
    for (int k = 0; k < 4; ++k) {
        int j = base + k;
        v[k] = (j < n) ? in[j] : 0;
        s += v[k];
    }
    red[t] = s;
    __syncthreads();
    for (int off = 1; off < 256; off <<= 1) {
        int u = (t >= off) ? red[t - off] : 0;
        __syncthreads();
        red[t] += u;
        __syncthreads();
    }
    int tbase = partial[b] + red[t] - s;
#pragma unroll
    for (int k = 0; k < 4; ++k) {
        int j = base + k;
        if (j < n) {
            out[j] = tbase;
            if (cursor) cursor[j] = tbase;
            tbase += v[k];
        }
    }
}

// ---------------- browptr via binary search on sorted batch ----------------
__global__ void k_bsearch(const int* __restrict__ batch, int* __restrict__ browptr,
                          int nN, int nG) {
    int g = blockIdx.x * blockDim.x + threadIdx.x;
    if (g > nG) return;
    int lo = 0, hi = nN;
    while (lo < hi) {
        int mid = (lo + hi) >> 1;
        if (batch[mid] < g) lo = mid + 1; else hi = mid;
    }
    browptr[g] = lo;
}

// ---------------- scatter edges into dst-buckets ----------------
__global__ void k_scatter(const int* __restrict__ src, const int* __restrict__ dst,
                          int* __restrict__ cursor, int* __restrict__ eidx, int E) {
    int e = blockIdx.x * blockDim.x + threadIdx.x;
    if (e >= E) return;
    int slot = atomicAdd(&cursor[dst[e]], 1);
    eidx[slot] = src[e];
}

// ---------------- W repack x3: fp32 [128][128] -> bf16 B-fragment order ----------------
// wpk[((kb*8+c16)*64 + lane)*8 + j] = bf16( W[kb*32 + (lane>>4)*8 + j][c16*16 + (lane&15)] )
__global__ void k_wpack3(const float* __restrict__ Wa, const float* __restrict__ Wb,
                         const float* __restrict__ Wc, unsigned short* __restrict__ wpk) {
    int gt = blockIdx.x * blockDim.x + threadIdx.x;  // 0..6143
    int m = gt >> 11, t = gt & 2047;
    const float* W = (m == 0) ? Wa : (m == 1) ? Wb : Wc;
    int lane = t & 63, fc = t >> 6;
    int kb = fc >> 3, c16 = fc & 7;
    int col = c16 * 16 + (lane & 15);
    int k0 = kb * 32 + (lane >> 4) * 8;
    unsigned r[4];
#pragma unroll
    for (int p = 0; p < 4; ++p) {
        float a = W[(size_t)(k0 + 2 * p) * H + col];
        float b = W[(size_t)(k0 + 2 * p + 1) * H + col];
        r[p] = f2bf2(a, b);
    }
    *(uint4*)(wpk + (size_t)m * 16384 + (size_t)t * 8) = make_uint4(r[0], r[1], r[2], r[3]);
}

// ---------------- gather-aggregate pos (C=2) ----------------
__global__ void k_gather_pos(const int* __restrict__ rowptr, const int* __restrict__ eidx,
                             const float* __restrict__ pos, float* __restrict__ agg, int nN) {
    int i = blockIdx.x * blockDim.x + threadIdx.x;
    if (i >= nN) return;
    int j0 = rowptr[i], j1 = rowptr[i + 1];
    float ax = 0.f, ay = 0.f;
    for (int j = j0; j < j1; ++j) {
        float2 p = ((const float2*)pos)[eidx[j]];
        ax += p.x; ay += p.y;
    }
    agg[i * 2 + 0] = ax;
    agg[i * 2 + 1] = ay;
}

// ---------------- gather + self-add, one WAVE per node (no divergence) ----------------
__global__ void k_gather_add(const int* __restrict__ rowptr, const int* __restrict__ eidx,
                             const unsigned short* __restrict__ x, unsigned short* __restrict__ out,
                             int nN) {
    int w = (blockIdx.x * blockDim.x + threadIdx.x) >> 6;  // node
    int lane = threadIdx.x & 63;
    if (w >= nN) return;
    const unsigned* xr = (const unsigned*)x;
    unsigned v = xr[(size_t)w * 64 + lane];
    float a0 = __uint_as_float(v << 16);
    float a1 = __uint_as_float(v & 0xFFFF0000u);
    int j0 = rowptr[w], j1 = rowptr[w + 1];
    for (int j = j0; j < j1; ++j) {
        int s = eidx[j];
        unsigned u = xr[(size_t)s * 64 + lane];
        a0 += __uint_as_float(u << 16);
        a1 += __uint_as_float(u & 0xFFFF0000u);
    }
    ((unsigned*)out)[(size_t)w * 64 + lane] = f2bf2(a0, a1);
}

// ---------------- first GIN1 linear: [N,2] -> [N,128] bf16, relu ----------------
__global__ void k_in2(const float* __restrict__ pos, const float* __restrict__ agg,
                      const float* __restrict__ W, const float* __restrict__ b,
                      unsigned short* __restrict__ out, int nN) {
    int idx = blockIdx.x * blockDim.x + threadIdx.x;
    int i = idx >> 5, q = idx & 31;
    if (i >= nN) return;
    float2 p = ((const float2*)pos)[i];
    float2 a = ((const float2*)agg)[i];
    float x0 = p.x + a.x, x1 = p.y + a.y;
    float4 w0 = ld4(&W[q * 4]);
    float4 w1 = ld4(&W[H + q * 4]);
    float4 bb = ld4(&b[q * 4]);
    float r0 = fmaxf(x0 * w0.x + x1 * w1.x + bb.x, 0.f);
    float r1 = fmaxf(x0 * w0.y + x1 * w1.y + bb.y, 0.f);
    float r2 = fmaxf(x0 * w0.z + x1 * w1.z + bb.z, 0.f);
    float r3 = fmaxf(x0 * w0.w + x1 * w1.w + bb.w, 0.f);
    *(uint2*)(out + (size_t)i * H + q * 4) = make_uint2(f2bf2(r0, r1), f2bf2(r2, r3));
}

// ---------------- MFMA matmul: out_bf16 = [BN](relu(x_bf16 @ W + b)) ----------------
template <bool HAS_BN>
__global__ __launch_bounds__(256) void k_mm_mfma(
    const unsigned short* __restrict__ xin, const unsigned short* __restrict__ wpk,
    const float* __restrict__ bias,
    const float* __restrict__ bn_g, const float* __restrict__ bn_b,
    const float* __restrict__ bn_rm, const float* __restrict__ bn_rv,
    unsigned short* __restrict__ out, int nN) {
    __shared__ unsigned short Wl[H * H];  // 32 KB bf16
    __shared__ float sB[H], sS[H], sH[H];
    const int t = threadIdx.x;

    {
        const uint4* s = (const uint4*)wpk;
        uint4* d = (uint4*)Wl;
#pragma unroll
        for (int r = 0; r < 8; ++r) d[r * 256 + t] = s[r * 256 + t];
    }
    if (t < H) {
        sB[t] = bias[t];
        if (HAS_BN) {
            float s = bn_g[t] * rsqrtf(bn_rv[t] + 1e-5f);
            sS[t] = s;
            sH[t] = bn_b[t] - bn_rm[t] * s;
        }
    }
    __syncthreads();

    const int lane = t & 63;
    const int wave = t >> 6;
    const int rowbase = blockIdx.x * 128 + wave * 32;
    const int lrow = lane & 15;
    const int lhi = lane >> 4;

    f32x4 acc[2][8];
#pragma unroll
    for (int rr = 0; rr < 2; ++rr)
#pragma unroll
        for (int c = 0; c < 8; ++c) acc[rr][c] = (f32x4){0.f, 0.f, 0.f, 0.f};

    const short8v* Wv = (const short8v*)Wl;

#pragma unroll
    for (int kb = 0; kb < 4; ++kb) {
        short8v xf[2];
#pragma unroll
        for (int rr = 0; rr < 2; ++rr) {
            int row = rowbase + rr * 16 + lrow;
            row = row < nN ? row : nN - 1;
            xf[rr] = *(const short8v*)(xin + (size_t)row * H + kb * 32 + lhi * 8);
        }
#pragma unroll
        for (int c16 = 0; c16 < 8; ++c16) {
            short8v wf = Wv[(kb * 8 + c16) * 64 + lane];
            acc[0][c16] = __builtin_amdgcn_mfma_f32_16x16x32_bf16(wf, xf[0], acc[0][c16], 0, 0, 0);
            acc[1][c16] = __builtin_amdgcn_mfma_f32_16x16x32_bf16(wf, xf[1], acc[1][c16], 0, 0, 0);
        }
    }

#pragma unroll
    for (int c16 = 0; c16 < 8; ++c16) {
        const int c0 = c16 * 16 + lhi * 4;
        float b0 = sB[c0], b1 = sB[c0 + 1], b2 = sB[c0 + 2], b3 = sB[c0 + 3];
        float s0, s1, s2, s3, h0, h1, h2, h3;
        if (HAS_BN) {
            s0 = sS[c0]; s1 = sS[c0 + 1]; s2 = sS[c0 + 2]; s3 = sS[c0 + 3];
            h0 = sH[c0]; h1 = sH[c0 + 1]; h2 = sH[c0 + 2]; h3 = sH[c0 + 3];
        }
#pragma unroll
        for (int rr = 0; rr < 2; ++rr) {
            int row = rowbase + rr * 16 + lrow;
            if (row >= nN) continue;
            float v0 = fmaxf(acc[rr][c16][0] + b0, 0.f);
            float v1 = fmaxf(acc[rr][c16][1] + b1, 0.f);
            float v2 = fmaxf(acc[rr][c16][2] + b2, 0.f);
            float v3 = fmaxf(acc[rr][c16][3] + b3, 0.f);
            if (HAS_BN) {
                v0 = v0 * s0 + h0; v1 = v1 * s1 + h1;
                v2 = v2 * s2 + h2; v3 = v3 * s3 + h3;
            }
            *(uint2*)(out + (size_t)row * H + c0) = make_uint2(f2bf2(v0, v1), f2bf2(v2, v3));
        }
    }
}

// ---------------- fused: pos-pool + fc (K=2) -> x0g ----------------
__global__ void k_fc_x0g(const float* __restrict__ pos, const int* __restrict__ browptr,
                         const float* __restrict__ W, const float* __restrict__ bias,
                         const float* __restrict__ g, const float* __restrict__ be,
                         const float* __restrict__ rm, const float* __restrict__ rv,
                         float* __restrict__ x0g) {
    __shared__ float sx[H], sy[H];
    int gi = blockIdx.x, t = threadIdx.x;
    int r0 = browptr[gi], r1 = browptr[gi + 1];
    float ax = 0.f, ay = 0.f;
    for (int r = r0 + t; r < r1; r += H) {
        float2 p = ((const float2*)pos)[r];
        ax += p.x; ay += p.y;
    }
    sx[t] = ax; sy[t] = ay;
    __syncthreads();
    for (int off = 64; off; off >>= 1) {
        if (t < off) { sx[t] += sx[t + off]; sy[t] += sy[t + off]; }
        __syncthreads();
    }
    float px = sx[0], py = sy[0];
    float acc = bias[t] + px * W[t] + py * W[H + t];
    acc = fmaxf(acc, 0.f);
    float s = g[t] * rsqrtf(rv[t] + 1e-5f);
    x0g[gi * H + t] = (acc - rm[t]) * s + be[t];
}

// ---------------- fused: pool(x_bf16) + add x0g + fc -> outg ----------------
__global__ void k_pool_fc(const unsigned short* __restrict__ x, const int* __restrict__ browptr,
                          const float* __restrict__ x0g,
                          const float* __restrict__ W, const float* __restrict__ bias,
                          const float* __restrict__ g, const float* __restrict__ be,
                          const float* __restrict__ rm, const float* __restrict__ rv,
                          float* __restrict__ outg) {
    __shared__ float row[H];
    int gi = blockIdx.x, t = threadIdx.x;
    int r0 = browptr[gi], r1 = browptr[gi + 1];
    float acc = 0.f;
    for (int r = r0; r < r1; ++r) acc += bf2f(x[(size_t)r * H + t]);
    row[t] = acc + x0g[gi * H + t];
    __syncthreads();
    float a = bias[t];
    for (int j = 0; j < H; ++j) a += row[j] * W[j * H + t];
    a = fmaxf(a, 0.f);
    float s = g[t] * rsqrtf(rv[t] + 1e-5f);
    outg[gi * H + t] = (a - rm[t]) * s + be[t];
}

// ---------------- fused: pool(x2) + x0g + x1g + fc + classifier -> out ----------------
__global__ void k_pool_fc_cls(const unsigned short* __restrict__ x, const int* __restrict__ browptr,
                              const float* __restrict__ x0g, const float* __restrict__ x1g,
                              const float* __restrict__ W, const float* __restrict__ bias,
                              const float* __restrict__ g, const float* __restrict__ be,
                              const float* __restrict__ rm, const float* __restrict__ rv,
                              const float* __restrict__ Wc1, const float* __restrict__ bc1,
                              const float* __restrict__ gc, const float* __restrict__ bec,
                              const float* __restrict__ rmc, const float* __restrict__ rvc,
                              const float* __restrict__ ap,
                              const float* __restrict__ Wc2, const float* __restrict__ bc2,
                              float* __restrict__ out) {
    __shared__ float row[H];
    __shared__ float x2r[H];
    __shared__ float hbuf[HC];
    int gi = blockIdx.x, t = threadIdx.x;
    int r0 = browptr[gi], r1 = browptr[gi + 1];
    float acc = 0.f;
    for (int r = r0; r < r1; ++r) acc += bf2f(x[(size_t)r * H + t]);
    row[t] = acc + x0g[gi * H + t] + x1g[gi * H + t];
    __syncthreads();
    float a = bias[t];
    for (int j = 0; j < H; ++j) a += row[j] * W[j * H + t];
    a = fmaxf(a, 0.f);
    float s = g[t] * rsqrtf(rv[t] + 1e-5f);
    x2r[t] = (a - rm[t]) * s + be[t];
    __syncthreads();
    if (t < HC) {
        float c = bc1[t];
        for (int j = 0; j < H; ++j) c += x2r[j] * Wc1[j * HC + t];
        float sc = gc[t] * rsqrtf(rvc[t] + 1e-5f);
        c = (c - rmc[t]) * sc + bec[t];
        float al = ap[0];
        hbuf[t] = c > 0.f ? c : al * c;
    }
    __syncthreads();
    if (t < NOUT) {
        float c = bc2[t];
        for (int j = 0; j < HC; ++j) c += hbuf[j] * Wc2[j * NOUT + t];
        out[gi * NOUT + t] = c;
    }
}

extern "C" void kernel_launch(void* const* d_in, const int* in_sizes, int n_in,
                              void* d_out, int out_size, void* d_ws, size_t ws_size,
                              hipStream_t stream) {
    const int N = kN, E = kE, G = kG;
    const float* pos = (const float*)d_in[0];
    const int* ei    = (const int*)d_in[1];
    const int* batch = (const int*)d_in[2];
    const float* W1a = (const float*)d_in[3];
    const float* b1a = (const float*)d_in[4];
    const float* W1b = (const float*)d_in[5];
    const float* b1b = (const float*)d_in[6];
    const float* n1g = (const float*)d_in[7];
    const float* n1b = (const float*)d_in[8];
    const float* n1rm = (const float*)d_in[9];
    const float* n1rv = (const float*)d_in[10];
    const float* W2a = (const float*)d_in[11];
    const float* b2a = (const float*)d_in[12];
    const float* W2b = (const float*)d_in[13];
    const float* b2b = (const float*)d_in[14];
    const float* n2g = (const float*)d_in[15];
    const float* n2b = (const float*)d_in[16];
    const float* n2rm = (const float*)d_in[17];
    const float* n2rv = (const float*)d_in[18];
    const float* Wf1 = (const float*)d_in[19];
    const float* bf1 = (const float*)d_in[20];
    const float* f1g = (const float*)d_in[21];
    const float* f1b = (const float*)d_in[22];
    const float* f1rm = (const float*)d_in[23];
    const float* f1rv = (const float*)d_in[24];
    const float* Wf2 = (const float*)d_in[25];
    const float* bf2 = (const float*)d_in[26];
    const float* f2g = (const float*)d_in[27];
    const float* f2b = (const float*)d_in[28];
    const float* f2rm = (const float*)d_in[29];
    const float* f2rv = (const float*)d_in[30];
    const float* Wc1 = (const float*)d_in[31];
    const float* bc1 = (const float*)d_in[32];
    const float* gc  = (const float*)d_in[33];
    const float* bec = (const float*)d_in[34];
    const float* rmc = (const float*)d_in[35];
    const float* rvc = (const float*)d_in[36];
    const float* ap  = (const float*)d_in[37];
    const float* Wc2 = (const float*)d_in[38];
    const float* bc2 = (const float*)d_in[39];
    float* out = (float*)d_out;

    // ---- workspace layout ----
    unsigned short* bh1 = (unsigned short*)d_ws;        // N*H bf16 (hA1 / s2 / x2)
    unsigned short* bx1 = bh1 + (size_t)N * H;          // N*H bf16 (x1 / hA2)
    unsigned short* wp  = bx1 + (size_t)N * H;          // 3*16384 (wp1|wp2|wp3)
    float* aggp  = (float*)(wp + 3 * 16384);            // N*2
    float* x0g   = aggp + (size_t)N * 2;                // G*H
    float* x1g   = x0g + (size_t)G * H;                 // G*H
    int* deg     = (int*)(x1g + (size_t)G * H);         // N (reused as cursor)
    int* rowptr  = deg + N;                             // N+1
    int* browptr = rowptr + N + 1;                      // G+1
    int* partial = browptr + G + 1;                     // 1024
    int* eidx    = partial + 1024;                      // E

    unsigned short* wp1 = wp;
    unsigned short* wp2 = wp + 16384;
    unsigned short* wp3 = wp + 32768;

    const int* src  = ei;
    const int* dstp = ei + E;
    const int nb = (N + 1023) / 1024;

    // ---- CSR build (by dst) + batch boundaries + W repack ----
    hipMemsetAsync(deg, 0, (size_t)N * sizeof(int), stream);
    k_wpack3<<<24, 256, 0, stream>>>(W1b, W2a, W2b, wp);
    k_hist<<<(E + 255) / 256, 256, 0, stream>>>(dstp, deg, E);
    k_bsearch<<<(G + 256) / 256, 256, 0, stream>>>(batch, browptr, N, G);
    k_scan_p1<<<nb, 256, 0, stream>>>(deg, partial, N);
    k_scan_p2<<<1, 1024, 0, stream>>>(partial, rowptr + N, nb);
    k_scan_p3<<<nb, 256, 0, stream>>>(deg, partial, rowptr, deg, N);
    k_scatter<<<(E + 255) / 256, 256, 0, stream>>>(src, dstp, deg, eidx, E);

    // ---- graph-level pos pooling + x0_g (fused) ----
    k_gather_pos<<<(N + 255) / 256, 256, 0, stream>>>(rowptr, eidx, pos, aggp, N);
    k_fc_x0g<<<G, H, 0, stream>>>(pos, browptr, Wf1, bf1, f1g, f1b, f1rm, f1rv, x0g);

    const int mmBlocks = (N + 127) / 128;

    // ---- GIN1: hA1 -> x1 ----
    k_in2<<<(N * 32 + 255) / 256, 256, 0, stream>>>(pos, aggp, W1a, b1a, bh1, N);
    k_mm_mfma<true><<<mmBlocks, 256, 0, stream>>>(bh1, wp1, b1b, n1g, n1b, n1rm, n1rv, bx1, N);

    // s2 = bf16(x1 + gather(x1)) -> bh1 ; x1_g = fc(x0g + pool(x1)) (fused)
    k_gather_add<<<(N * 64 + 255) / 256, 256, 0, stream>>>(rowptr, eidx, bx1, bh1, N);
    k_pool_fc<<<G, H, 0, stream>>>(bx1, browptr, x0g, Wf2, bf2, f2g, f2b, f2rm, f2rv, x1g);

    // ---- GIN2: hA2 = relu(s2@W2a+b2a) -> bx1 ; x2 = BN(relu(hA2@W2b+b2b)) -> bh1 ----
    k_mm_mfma<false><<<mmBlocks, 256, 0, stream>>>(bh1, wp2, b2a, nullptr, nullptr, nullptr, nullptr, bx1, N);
    k_mm_mfma<true><<<mmBlocks, 256, 0, stream>>>(bx1, wp3, b2b, n2g, n2b, n2rm, n2rv, bh1, N);

    // ---- x2_g + classifier (fused) ----
    k_pool_fc_cls<<<G, H, 0, stream>>>(bh1, browptr, x0g, x1g, Wf2, bf2, f2g, f2b, f2rm, f2rv,
                                       Wc1, bc1, gc, bec, rmc, rvc, ap, Wc2, bc2, out);
}

// Round 6
// 276.647 us; speedup vs baseline: 1.1008x; 1.1008x over previous
//
#include <hip/hip_runtime.h>

#define H 128
#define HC 64
#define NOUT 10

static constexpr int kN = 100000;
static constexpr int kE = 600000;
static constexpr int kG = 1000;

typedef __attribute__((ext_vector_type(8))) short short8v;
typedef __attribute__((ext_vector_type(4))) float f32x4;

__device__ __forceinline__ float4 ld4(const float* p) { return *(const float4*)p; }

// fp32 -> bf16 round-to-nearest-even
__device__ __forceinline__ unsigned f2bf(float f) {
    unsigned u = __float_as_uint(f);
    return (u + 0x7fffu + ((u >> 16) & 1u)) >> 16;
}
__device__ __forceinline__ unsigned f2bf2(float a, float b) {
    return f2bf(a) | (f2bf(b) << 16);
}
__device__ __forceinline__ float bf2f(unsigned short u) {
    return __uint_as_float(((unsigned)u) << 16);
}
__device__ __forceinline__ void unpack_add8(uint4 u, float* a) {
    a[0] += __uint_as_float(u.x << 16); a[1] += __uint_as_float(u.x & 0xFFFF0000u);
    a[2] += __uint_as_float(u.y << 16); a[3] += __uint_as_float(u.y & 0xFFFF0000u);
    a[4] += __uint_as_float(u.z << 16); a[5] += __uint_as_float(u.z & 0xFFFF0000u);
    a[6] += __uint_as_float(u.w << 16); a[7] += __uint_as_float(u.w & 0xFFFF0000u);
}

// LDS tile swizzle: ushort-index XOR mask for row rl (flips granule bits 3-6)
__device__ __forceinline__ int swzmask(int rl) { return (rl & 15) << 3; }

// ---------------- histogram ----------------
__global__ void k_hist(const int* __restrict__ keys, int* __restrict__ cnt, int n) {
    int i = blockIdx.x * blockDim.x + threadIdx.x;
    if (i < n) atomicAdd(&cnt[keys[i]], 1);
}

// ---------------- hierarchical scan ----------------
__global__ void k_scan_p1(const int* __restrict__ in, int* __restrict__ partial, int n) {
    __shared__ int red[256];
    int b = blockIdx.x, t = threadIdx.x;
    int base = b * 1024 + t * 4;
    int s = 0;
#pragma unroll
    for (int k = 0; k < 4; ++k) {
        int j = base + k;
        if (j < n) s += in[j];
    }
    red[t] = s;
    __syncthreads();
    for (int off = 128; off; off >>= 1) {
        if (t < off) red[t] += red[t + off];
        __syncthreads();
    }
    if (t == 0) partial[b] = red[0];
}

__global__ void k_scan_p2(int* __restrict__ partial, int* __restrict__ total_out, int nb) {
    __shared__ int ssum[1024];
    int t = threadIdx.x;
    int v = (t < nb) ? partial[t] : 0;
    ssum[t] = v;
    __syncthreads();
    for (int off = 1; off < 1024; off <<= 1) {
        int u = (t >= off) ? ssum[t - off] : 0;
        __syncthreads();
        ssum[t] += u;
        __syncthreads();
    }
    if (t < nb) partial[t] = ssum[t] - v;
    if (t == 1023 && total_out) *total_out = ssum[1023];
}

__global__ void k_scan_p3(const int* __restrict__ in, const int* __restrict__ partial,
                          int* __restrict__ out, int* __restrict__ cursor, int n) {
    __shared__ int red[256];
    int b = blockIdx.x, t = threadIdx.x;
    int base = b * 1024 + t * 4;
    int v[4];
    int s = 0;
#pragma unroll
    for (int k = 0; k < 4; ++k) {
        int j = base + k;
        v[k] = (j < n) ? in[j] : 0;
        s += v[k];
    }
    red[t] = s;
    __syncthreads();
    for (int off = 1; off < 256; off <<= 1) {
        int u = (t >= off) ? red[t - off] : 0;
        __syncthreads();
        red[t] += u;
        __syncthreads();
    }
    int tbase = partial[b] + red[t] - s;
#pragma unroll
    for (int k = 0; k < 4; ++k) {
        int j = base + k;
        if (j < n) {
            out[j] = tbase;
            if (cursor) cursor[j] = tbase;
            tbase += v[k];
        }
    }
}

// ---------------- browptr via binary search on sorted batch ----------------
__global__ void k_bsearch(const int* __restrict__ batch, int* __restrict__ browptr,
                          int nN, int nG) {
    int g = blockIdx.x * blockDim.x + threadIdx.x;
    if (g > nG) return;
    int lo = 0, hi = nN;
    while (lo < hi) {
        int mid = (lo + hi) >> 1;
        if (batch[mid] < g) lo = mid + 1; else hi = mid;
    }
    browptr[g] = lo;
}

// ---------------- scatter edges into dst-buckets ----------------
__global__ void k_scatter(const int* __restrict__ src, const int* __restrict__ dst,
                          int* __restrict__ cursor, int* __restrict__ eidx, int E) {
    int e = blockIdx.x * blockDim.x + threadIdx.x;
    if (e >= E) return;
    int slot = atomicAdd(&cursor[dst[e]], 1);
    eidx[slot] = src[e];
}

// ---------------- W repack x3: fp32 [128][128] -> bf16 B-fragment order ----------------
__global__ void k_wpack3(const float* __restrict__ Wa, const float* __restrict__ Wb,
                         const float* __restrict__ Wc, unsigned short* __restrict__ wpk) {
    int gt = blockIdx.x * blockDim.x + threadIdx.x;  // 0..6143
    int m = gt >> 11, t = gt & 2047;
    const float* W = (m == 0) ? Wa : (m == 1) ? Wb : Wc;
    int lane = t & 63, fc = t >> 6;
    int kb = fc >> 3, c16 = fc & 7;
    int col = c16 * 16 + (lane & 15);
    int k0 = kb * 32 + (lane >> 4) * 8;
    unsigned r[4];
#pragma unroll
    for (int p = 0; p < 4; ++p) {
        float a = W[(size_t)(k0 + 2 * p) * H + col];
        float b = W[(size_t)(k0 + 2 * p + 1) * H + col];
        r[p] = f2bf2(a, b);
    }
    *(uint4*)(wpk + (size_t)m * 16384 + (size_t)t * 8) = make_uint4(r[0], r[1], r[2], r[3]);
}

// ---------------- gather-aggregate pos (C=2) ----------------
__global__ void k_gather_pos(const int* __restrict__ rowptr, const int* __restrict__ eidx,
                             const float* __restrict__ pos, float* __restrict__ agg, int nN) {
    int i = blockIdx.x * blockDim.x + threadIdx.x;
    if (i >= nN) return;
    int j0 = rowptr[i], j1 = rowptr[i + 1];
    float ax = 0.f, ay = 0.f;
    for (int j = j0; j < j1; ++j) {
        float2 p = ((const float2*)pos)[eidx[j]];
        ax += p.x; ay += p.y;
    }
    agg[i * 2 + 0] = ax;
    agg[i * 2 + 1] = ay;
}

// ---------------- gather + self-add (R4 version: 16 lanes/node, uint4 loads) ----------------
__global__ void k_gather_add(const int* __restrict__ rowptr, const int* __restrict__ eidx,
                             const unsigned short* __restrict__ x, unsigned short* __restrict__ out,
                             int nN) {
    int idx = blockIdx.x * blockDim.x + threadIdx.x;
    int i = idx >> 4, q = idx & 15;  // q: 8-elem chunk
    if (i >= nN) return;
    const int off = q * 8;
    float a[8] = {0, 0, 0, 0, 0, 0, 0, 0};
    unpack_add8(*(const uint4*)(x + (size_t)i * H + off), a);
    int j0 = rowptr[i], j1 = rowptr[i + 1];
    for (int j = j0; j < j1; ++j) {
        int s = eidx[j];
        unpack_add8(*(const uint4*)(x + (size_t)s * H + off), a);
    }
    *(uint4*)(out + (size_t)i * H + off) =
        make_uint4(f2bf2(a[0], a[1]), f2bf2(a[2], a[3]), f2bf2(a[4], a[5]), f2bf2(a[6], a[7]));
}

// ---------------- fused GIN1: hA1 tile (K=2) in LDS -> MFMA mm -> BN -> x1 ----------------
__global__ __launch_bounds__(256) void k_gin1(
    const float* __restrict__ pos, const float* __restrict__ aggp,
    const float* __restrict__ W1a, const float* __restrict__ b1a,
    const short8v* __restrict__ wpk, const float* __restrict__ bias,
    const float* __restrict__ bn_g, const float* __restrict__ bn_b,
    const float* __restrict__ bn_rm, const float* __restrict__ bn_rv,
    unsigned short* __restrict__ out, int nN) {
    __shared__ unsigned short As[H * H];  // 32 KB swizzled bf16 tile
    __shared__ float sB[H], sS[H], sH2[H];
    const int t = threadIdx.x;

    if (t < H) {
        sB[t] = bias[t];
        float s = bn_g[t] * rsqrtf(bn_rv[t] + 1e-5f);
        sS[t] = s;
        sH2[t] = bn_b[t] - bn_rm[t] * s;
    }

    // phase 0: compute hA1 = relu((pos+agg)@W1a + b1a) tile into LDS
    {
        const int rl = t >> 1, half = t & 1;
        const int rc = min(blockIdx.x * 128 + rl, nN - 1);
        float2 p = ((const float2*)pos)[rc];
        float2 a = ((const float2*)aggp)[rc];
        const float x0 = p.x + a.x, x1 = p.y + a.y;
        const int mask = swzmask(rl);
#pragma unroll
        for (int c4 = 0; c4 < 16; ++c4) {
            int c = half * 64 + c4 * 4;
            float4 w0 = ld4(&W1a[c]);
            float4 w1 = ld4(&W1a[H + c]);
            float4 bb = ld4(&b1a[c]);
            float r0 = fmaxf(x0 * w0.x + x1 * w1.x + bb.x, 0.f);
            float r1 = fmaxf(x0 * w0.y + x1 * w1.y + bb.y, 0.f);
            float r2 = fmaxf(x0 * w0.z + x1 * w1.z + bb.z, 0.f);
            float r3 = fmaxf(x0 * w0.w + x1 * w1.w + bb.w, 0.f);
            int idx = rl * H + c;
            *(uint2*)(As + (idx ^ mask)) = make_uint2(f2bf2(r0, r1), f2bf2(r2, r3));
        }
    }
    __syncthreads();

    const int lane = t & 63;
    const int wave = t >> 6;
    const int rowbase = blockIdx.x * 128 + wave * 32;
    const int lrow = lane & 15;
    const int lhi = lane >> 4;

    f32x4 acc[2][8];
#pragma unroll
    for (int rr = 0; rr < 2; ++rr)
#pragma unroll
        for (int c = 0; c < 8; ++c) acc[rr][c] = (f32x4){0.f, 0.f, 0.f, 0.f};

#pragma unroll
    for (int kb = 0; kb < 4; ++kb) {
        short8v xf[2];
#pragma unroll
        for (int rr = 0; rr < 2; ++rr) {
            int rl = wave * 32 + rr * 16 + lrow;
            int idx = rl * H + kb * 32 + lhi * 8;
            xf[rr] = *(const short8v*)(As + (idx ^ swzmask(rl)));
        }
#pragma unroll
        for (int c16 = 0; c16 < 8; ++c16) {
            short8v wf = wpk[(kb * 8 + c16) * 64 + lane];
            acc[0][c16] = __builtin_amdgcn_mfma_f32_16x16x32_bf16(wf, xf[0], acc[0][c16], 0, 0, 0);
            acc[1][c16] = __builtin_amdgcn_mfma_f32_16x16x32_bf16(wf, xf[1], acc[1][c16], 0, 0, 0);
        }
    }

#pragma unroll
    for (int c16 = 0; c16 < 8; ++c16) {
        const int c0 = c16 * 16 + lhi * 4;
        float b0 = sB[c0], b1 = sB[c0 + 1], b2 = sB[c0 + 2], b3 = sB[c0 + 3];
        float s0 = sS[c0], s1 = sS[c0 + 1], s2 = sS[c0 + 2], s3 = sS[c0 + 3];
        float h0 = sH2[c0], h1 = sH2[c0 + 1], h2 = sH2[c0 + 2], h3 = sH2[c0 + 3];
#pragma unroll
        for (int rr = 0; rr < 2; ++rr) {
            int row = rowbase + rr * 16 + lrow;
            if (row >= nN) continue;
            float v0 = fmaxf(acc[rr][c16][0] + b0, 0.f) * s0 + h0;
            float v1 = fmaxf(acc[rr][c16][1] + b1, 0.f) * s1 + h1;
            float v2 = fmaxf(acc[rr][c16][2] + b2, 0.f) * s2 + h2;
            float v3 = fmaxf(acc[rr][c16][3] + b3, 0.f) * s3 + h3;
            *(uint2*)(out + (size_t)row * H + c0) = make_uint2(f2bf2(v0, v1), f2bf2(v2, v3));
        }
    }
}

// ---------------- fused GIN2: mmA (relu) -> LDS -> mmB -> BN -> x2 (in-place ok) ----------------
__global__ __launch_bounds__(256) void k_gin2(
    const unsigned short* __restrict__ xin, const short8v* __restrict__ wpA,
    const float* __restrict__ biasA, const short8v* __restrict__ wpB,
    const float* __restrict__ biasB,
    const float* __restrict__ bn_g, const float* __restrict__ bn_b,
    const float* __restrict__ bn_rm, const float* __restrict__ bn_rv,
    unsigned short* __restrict__ out, int nN) {
    __shared__ unsigned short As[H * H];  // 32 KB swizzled bf16 tile (hA2)
    __shared__ float sBa[H], sBb[H], sS[H], sH2[H];
    const int t = threadIdx.x;

    if (t < H) {
        sBa[t] = biasA[t];
        sBb[t] = biasB[t];
        float s = bn_g[t] * rsqrtf(bn_rv[t] + 1e-5f);
        sS[t] = s;
        sH2[t] = bn_b[t] - bn_rm[t] * s;
    }
    __syncthreads();

    const int lane = t & 63;
    const int wave = t >> 6;
    const int rowbase = blockIdx.x * 128 + wave * 32;
    const int lrow = lane & 15;
    const int lhi = lane >> 4;

    f32x4 acc[2][8];
#pragma unroll
    for (int rr = 0; rr < 2; ++rr)
#pragma unroll
        for (int c = 0; c < 8; ++c) acc[rr][c] = (f32x4){0.f, 0.f, 0.f, 0.f};

    // phase 1: hA2 = relu(s2 @ W2a + b2a), xf from global
#pragma unroll
    for (int kb = 0; kb < 4; ++kb) {
        short8v xf[2];
#pragma unroll
        for (int rr = 0; rr < 2; ++rr) {
            int row = rowbase + rr * 16 + lrow;
            row = row < nN ? row : nN - 1;
            xf[rr] = *(const short8v*)(xin + (size_t)row * H + kb * 32 + lhi * 8);
        }
#pragma unroll
        for (int c16 = 0; c16 < 8; ++c16) {
            short8v wf = wpA[(kb * 8 + c16) * 64 + lane];
            acc[0][c16] = __builtin_amdgcn_mfma_f32_16x16x32_bf16(wf, xf[0], acc[0][c16], 0, 0, 0);
            acc[1][c16] = __builtin_amdgcn_mfma_f32_16x16x32_bf16(wf, xf[1], acc[1][c16], 0, 0, 0);
        }
    }

    // epilogue 1 -> swizzled LDS
#pragma unroll
    for (int c16 = 0; c16 < 8; ++c16) {
        const int c0 = c16 * 16 + lhi * 4;
        float b0 = sBa[c0], b1 = sBa[c0 + 1], b2 = sBa[c0 + 2], b3 = sBa[c0 + 3];
#pragma unroll
        for (int rr = 0; rr < 2; ++rr) {
            int rl = wave * 32 + rr * 16 + lrow;
            float v0 = fmaxf(acc[rr][c16][0] + b0, 0.f);
            float v1 = fmaxf(acc[rr][c16][1] + b1, 0.f);
            float v2 = fmaxf(acc[rr][c16][2] + b2, 0.f);
            float v3 = fmaxf(acc[rr][c16][3] + b3, 0.f);
            int idx = rl * H + c0;
            *(uint2*)(As + (idx ^ swzmask(rl))) = make_uint2(f2bf2(v0, v1), f2bf2(v2, v3));
        }
    }
    __syncthreads();

    // phase 2: x2 = BN(relu(hA2 @ W2b + b2b)), xf from LDS
#pragma unroll
    for (int rr = 0; rr < 2; ++rr)
#pragma unroll
        for (int c = 0; c < 8; ++c) acc[rr][c] = (f32x4){0.f, 0.f, 0.f, 0.f};

#pragma unroll
    for (int kb = 0; kb < 4; ++kb) {
        short8v xf[2];
#pragma unroll
        for (int rr = 0; rr < 2; ++rr) {
            int rl = wave * 32 + rr * 16 + lrow;
            int idx = rl * H + kb * 32 + lhi * 8;
            xf[rr] = *(const short8v*)(As + (idx ^ swzmask(rl)));
        }
#pragma unroll
        for (int c16 = 0; c16 < 8; ++c16) {
            short8v wf = wpB[(kb * 8 + c16) * 64 + lane];
            acc[0][c16] = __builtin_amdgcn_mfma_f32_16x16x32_bf16(wf, xf[0], acc[0][c16], 0, 0, 0);
            acc[1][c16] = __builtin_amdgcn_mfma_f32_16x16x32_bf16(wf, xf[1], acc[1][c16], 0, 0, 0);
        }
    }

#pragma unroll
    for (int c16 = 0; c16 < 8; ++c16) {
        const int c0 = c16 * 16 + lhi * 4;
        float b0 = sBb[c0], b1 = sBb[c0 + 1], b2 = sBb[c0 + 2], b3 = sBb[c0 + 3];
        float s0 = sS[c0], s1 = sS[c0 + 1], s2 = sS[c0 + 2], s3 = sS[c0 + 3];
        float h0 = sH2[c0], h1 = sH2[c0 + 1], h2 = sH2[c0 + 2], h3 = sH2[c0 + 3];
#pragma unroll
        for (int rr = 0; rr < 2; ++rr) {
            int row = rowbase + rr * 16 + lrow;
            if (row >= nN) continue;
            float v0 = fmaxf(acc[rr][c16][0] + b0, 0.f) * s0 + h0;
            float v1 = fmaxf(acc[rr][c16][1] + b1, 0.f) * s1 + h1;
            float v2 = fmaxf(acc[rr][c16][2] + b2, 0.f) * s2 + h2;
            float v3 = fmaxf(acc[rr][c16][3] + b3, 0.f) * s3 + h3;
            *(uint2*)(out + (size_t)row * H + c0) = make_uint2(f2bf2(v0, v1), f2bf2(v2, v3));
        }
    }
}

// ---------------- fused: pos-pool + fc (K=2) -> x0g ----------------
__global__ void k_fc_x0g(const float* __restrict__ pos, const int* __restrict__ browptr,
                         const float* __restrict__ W, const float* __restrict__ bias,
                         const float* __restrict__ g, const float* __restrict__ be,
                         const float* __restrict__ rm, const float* __restrict__ rv,
                         float* __restrict__ x0g) {
    __shared__ float sx[H], sy[H];
    int gi = blockIdx.x, t = threadIdx.x;
    int r0 = browptr[gi], r1 = browptr[gi + 1];
    float ax = 0.f, ay = 0.f;
    for (int r = r0 + t; r < r1; r += H) {
        float2 p = ((const float2*)pos)[r];
        ax += p.x; ay += p.y;
    }
    sx[t] = ax; sy[t] = ay;
    __syncthreads();
    for (int off = 64; off; off >>= 1) {
        if (t < off) { sx[t] += sx[t + off]; sy[t] += sy[t + off]; }
        __syncthreads();
    }
    float px = sx[0], py = sy[0];
    float acc = bias[t] + px * W[t] + py * W[H + t];
    acc = fmaxf(acc, 0.f);
    float s = g[t] * rsqrtf(rv[t] + 1e-5f);
    x0g[gi * H + t] = (acc - rm[t]) * s + be[t];
}

// ---------------- fused: pool(x_bf16) + add x0g + fc -> outg ----------------
__global__ void k_pool_fc(const unsigned short* __restrict__ x, const int* __restrict__ browptr,
                          const float* __restrict__ x0g,
                          const float* __restrict__ W, const float* __restrict__ bias,
                          const float* __restrict__ g, const float* __restrict__ be,
                          const float* __restrict__ rm, const float* __restrict__ rv,
                          float* __restrict__ outg) {
    __shared__ float row[H];
    int gi = blockIdx.x, t = threadIdx.x;
    int r0 = browptr[gi], r1 = browptr[gi + 1];
    float acc = 0.f;
    for (int r = r0; r < r1; ++r) acc += bf2f(x[(size_t)r * H + t]);
    row[t] = acc + x0g[gi * H + t];
    __syncthreads();
    float a = bias[t];
    for (int j = 0; j < H; ++j) a += row[j] * W[j * H + t];
    a = fmaxf(a, 0.f);
    float s = g[t] * rsqrtf(rv[t] + 1e-5f);
    outg[gi * H + t] = (a - rm[t]) * s + be[t];
}

// ---------------- fused: pool(x2) + x0g + x1g + fc + classifier -> out ----------------
__global__ void k_pool_fc_cls(const unsigned short* __restrict__ x, const int* __restrict__ browptr,
                              const float* __restrict__ x0g, const float* __restrict__ x1g,
                              const float* __restrict__ W, const float* __restrict__ bias,
                              const float* __restrict__ g, const float* __restrict__ be,
                              const float* __restrict__ rm, const float* __restrict__ rv,
                              const float* __restrict__ Wc1, const float* __restrict__ bc1,
                              const float* __restrict__ gc, const float* __restrict__ bec,
                              const float* __restrict__ rmc, const float* __restrict__ rvc,
                              const float* __restrict__ ap,
                              const float* __restrict__ Wc2, const float* __restrict__ bc2,
                              float* __restrict__ out) {
    __shared__ float row[H];
    __shared__ float x2r[H];
    __shared__ float hbuf[HC];
    int gi = blockIdx.x, t = threadIdx.x;
    int r0 = browptr[gi], r1 = browptr[gi + 1];
    float acc = 0.f;
    for (int r = r0; r < r1; ++r) acc += bf2f(x[(size_t)r * H + t]);
    row[t] = acc + x0g[gi * H + t] + x1g[gi * H + t];
    __syncthreads();
    float a = bias[t];
    for (int j = 0; j < H; ++j) a += row[j] * W[j * H + t];
    a = fmaxf(a, 0.f);
    float s = g[t] * rsqrtf(rv[t] + 1e-5f);
    x2r[t] = (a - rm[t]) * s + be[t];
    __syncthreads();
    if (t < HC) {
        float c = bc1[t];
        for (int j = 0; j < H; ++j) c += x2r[j] * Wc1[j * HC + t];
        float sc = gc[t] * rsqrtf(rvc[t] + 1e-5f);
        c = (c - rmc[t]) * sc + bec[t];
        float al = ap[0];
        hbuf[t] = c > 0.f ? c : al * c;
    }
    __syncthreads();
    if (t < NOUT) {
        float c = bc2[t];
        for (int j = 0; j < HC; ++j) c += hbuf[j] * Wc2[j * NOUT + t];
        out[gi * NOUT + t] = c;
    }
}

extern "C" void kernel_launch(void* const* d_in, const int* in_sizes, int n_in,
                              void* d_out, int out_size, void* d_ws, size_t ws_size,
                              hipStream_t stream) {
    const int N = kN, E = kE, G = kG;
    const float* pos = (const float*)d_in[0];
    const int* ei    = (const int*)d_in[1];
    const int* batch = (const int*)d_in[2];
    const float* W1a = (const float*)d_in[3];
    const float* b1a = (const float*)d_in[4];
    const float* W1b = (const float*)d_in[5];
    const float* b1b = (const float*)d_in[6];
    const float* n1g = (const float*)d_in[7];
    const float* n1b = (const float*)d_in[8];
    const float* n1rm = (const float*)d_in[9];
    const float* n1rv = (const float*)d_in[10];
    const float* W2a = (const float*)d_in[11];
    const float* b2a = (const float*)d_in[12];
    const float* W2b = (const float*)d_in[13];
    const float* b2b = (const float*)d_in[14];
    const float* n2g = (const float*)d_in[15];
    const float* n2b = (const float*)d_in[16];
    const float* n2rm = (const float*)d_in[17];
    const float* n2rv = (const float*)d_in[18];
    const float* Wf1 = (const float*)d_in[19];
    const float* bf1 = (const float*)d_in[20];
    const float* f1g = (const float*)d_in[21];
    const float* f1b = (const float*)d_in[22];
    const float* f1rm = (const float*)d_in[23];
    const float* f1rv = (const float*)d_in[24];
    const float* Wf2 = (const float*)d_in[25];
    const float* bf2 = (const float*)d_in[26];
    const float* f2g = (const float*)d_in[27];
    const float* f2b = (const float*)d_in[28];
    const float* f2rm = (const float*)d_in[29];
    const float* f2rv = (const float*)d_in[30];
    const float* Wc1 = (const float*)d_in[31];
    const float* bc1 = (const float*)d_in[32];
    const float* gc  = (const float*)d_in[33];
    const float* bec = (const float*)d_in[34];
    const float* rmc = (const float*)d_in[35];
    const float* rvc = (const float*)d_in[36];
    const float* ap  = (const float*)d_in[37];
    const float* Wc2 = (const float*)d_in[38];
    const float* bc2 = (const float*)d_in[39];
    float* out = (float*)d_out;

    // ---- workspace layout ----
    unsigned short* bh1 = (unsigned short*)d_ws;        // N*H bf16 (hA1-stage out / s2 / x2)
    unsigned short* bx1 = bh1 + (size_t)N * H;          // N*H bf16 (x1)
    unsigned short* wp  = bx1 + (size_t)N * H;          // 3*16384 (wp1|wp2|wp3)
    float* aggp  = (float*)(wp + 3 * 16384);            // N*2
    float* x0g   = aggp + (size_t)N * 2;                // G*H
    float* x1g   = x0g + (size_t)G * H;                 // G*H
    int* deg     = (int*)(x1g + (size_t)G * H);         // N (reused as cursor)
    int* rowptr  = deg + N;                             // N+1
    int* browptr = rowptr + N + 1;                      // G+1
    int* partial = browptr + G + 1;                     // 1024
    int* eidx    = partial + 1024;                      // E

    const short8v* wp1 = (const short8v*)wp;
    const short8v* wp2 = (const short8v*)(wp + 16384);
    const short8v* wp3 = (const short8v*)(wp + 32768);

    const int* src  = ei;
    const int* dstp = ei + E;
    const int nb = (N + 1023) / 1024;

    // ---- CSR build (by dst) + batch boundaries + W repack ----
    hipMemsetAsync(deg, 0, (size_t)N * sizeof(int), stream);
    k_wpack3<<<24, 256, 0, stream>>>(W1b, W2a, W2b, wp);
    k_hist<<<(E + 255) / 256, 256, 0, stream>>>(dstp, deg, E);
    k_bsearch<<<(G + 256) / 256, 256, 0, stream>>>(batch, browptr, N, G);
    k_scan_p1<<<nb, 256, 0, stream>>>(deg, partial, N);
    k_scan_p2<<<1, 1024, 0, stream>>>(partial, rowptr + N, nb);
    k_scan_p3<<<nb, 256, 0, stream>>>(deg, partial, rowptr, deg, N);
    k_scatter<<<(E + 255) / 256, 256, 0, stream>>>(src, dstp, deg, eidx, E);

    // ---- graph-level pos pooling + x0_g ----
    k_gather_pos<<<(N + 255) / 256, 256, 0, stream>>>(rowptr, eidx, pos, aggp, N);
    k_fc_x0g<<<G, H, 0, stream>>>(pos, browptr, Wf1, bf1, f1g, f1b, f1rm, f1rv, x0g);

    const int mmBlocks = (N + 127) / 128;

    // ---- GIN1 fused: x1 = BN(relu(hA1@W1b+b1b)), hA1 staged in LDS ----
    k_gin1<<<mmBlocks, 256, 0, stream>>>(pos, aggp, W1a, b1a, wp1, b1b,
                                         n1g, n1b, n1rm, n1rv, bx1, N);

    // s2 = bf16(x1 + gather(x1)) -> bh1 ; x1_g = fc(x0g + pool(x1)) ----
    k_gather_add<<<(N * 16 + 255) / 256, 256, 0, stream>>>(rowptr, eidx, bx1, bh1, N);
    k_pool_fc<<<G, H, 0, stream>>>(bx1, browptr, x0g, Wf2, bf2, f2g, f2b, f2rm, f2rv, x1g);

    // ---- GIN2 fused: x2 = BN(relu(relu(s2@W2a+b2a)@W2b+b2b)) in-place bh1 ----
    k_gin2<<<mmBlocks, 256, 0, stream>>>(bh1, wp2, b2a, wp3, b2b,
                                         n2g, n2b, n2rm, n2rv, bh1, N);

    // ---- x2_g + classifier (fused) ----
    k_pool_fc_cls<<<G, H, 0, stream>>>(bh1, browptr, x0g, x1g, Wf2, bf2, f2g, f2b, f2rm, f2rv,
                                       Wc1, bc1, gc, bec, rmc, rvc, ap, Wc2, bc2, out);
}